// Round 9
// baseline (741.750 us; speedup 1.0000x reference)
//
#include <hip/hip_runtime.h>
#include <stdint.h>

#define NN3 262144
#define NN2 65536
#define NN1 16384

typedef __attribute__((ext_vector_type(8))) __bf16 bf16x8;
typedef __attribute__((ext_vector_type(4))) float floatx4;
typedef __attribute__((ext_vector_type(4))) unsigned int uintx4;

static __device__ __forceinline__ float bf2f(unsigned short u) {
    union { unsigned int i; float f; } v; v.i = ((unsigned int)u) << 16; return v.f;
}
static __device__ __forceinline__ unsigned short f2bf(float f) {
    union { float f; unsigned int i; } v; v.f = f;
    unsigned int x = v.i;
    return (unsigned short)((x + 0x7fffu + ((x >> 16) & 1u)) >> 16);
}
static __device__ __forceinline__ bf16x8 zero_bf16x8() {
    bf16x8 z;
#pragma unroll
    for (int i = 0; i < 8; ++i) z[i] = (__bf16)0.0f;
    return z;
}

struct Params {
    const float* features;
    const int* neighs3; const int* neighs2; const int* neighs1;
    const float* w_enc1; const float* b_enc1;
    const float* w_enc2; const float* b_enc2;
    const float* w_enc3; const float* b_enc3;
    const float* w_dec1; const float* b_dec1;
    const float* w_dec2; const float* b_dec2;
    const float* w_head; const float* b_head;
    unsigned short* wb_enc2; unsigned short* wb_enc3;
    unsigned short* wb_dec1; unsigned short* wb_dec2;
    unsigned short* x7p; unsigned short* x6p; unsigned short* x6;
    unsigned short* x7dec; unsigned short* x8dec;
    unsigned int* bar;
    float* out;
};

// ---------------- software grid barrier, round-5 bug fixed ----------------
// Round 5 regressed 5x because the spin polled with ACQUIRE loads: LLVM emits a
// full L2 buffer_inv per acquire at agent scope -> thousands of L2 invalidates
// per block per barrier. Fix: RELAXED polls (plain coherent load, no cache op);
// exactly ONE release fence (wbL2) before arrival and ONE acquire fence (inv)
// after the spin, per block per barrier. Co-residency by construction:
// 1024 blocks = 4/CU x 256 CU, __launch_bounds__(256,4), ~10KB LDS.
// Hang-guard: bail after 1M polls -> wrong answer (bench feedback), never a hang.
static __device__ __forceinline__ void gridsync(unsigned int* bar, unsigned int target) {
    __syncthreads();
    if (threadIdx.x == 0) {
        __builtin_amdgcn_fence(__ATOMIC_RELEASE, "agent");   // one wbL2
        __hip_atomic_fetch_add(bar, 1u, __ATOMIC_RELAXED, __HIP_MEMORY_SCOPE_AGENT);
        unsigned int spins = 0;
        while (__hip_atomic_load(bar, __ATOMIC_RELAXED, __HIP_MEMORY_SCOPE_AGENT) < target) {
            __builtin_amdgcn_s_sleep(2);
            if (++spins > (1u << 20)) break;                 // hang-guard
        }
        __builtin_amdgcn_fence(__ATOMIC_ACQUIRE, "agent");   // one inv
    }
    __syncthreads();
}

__global__ __launch_bounds__(64) void init_bar(unsigned int* bar) {
    if (threadIdx.x < 8) bar[threadIdx.x] = 0u;
}

// ---------------- swizzled weight prep ----------------
//   out[((n*KT + kt)*64 + lane)*8 + e] = w[(n*16 + m)*K + kt*32 + quad*8 + e], k>=K zero-pad.
template <int CIN, int COUT>
static __device__ __forceinline__ void prep_swz(const float* __restrict__ w,
                                                unsigned short* __restrict__ out, int g) {
    constexpr int K = 9 * CIN, KT = (K + 31) / 32;
    int n = g / (KT * 512);
    int r = g - n * (KT * 512);
    int kt = r >> 9;
    int q = r & 511;
    int lane = q >> 3, e = q & 7;
    int m = lane & 15, quad = lane >> 4;
    int k = kt * 32 + quad * 8 + e;
    float v = (k < K) ? w[(n * 16 + m) * K + k] : 0.0f;
    out[g] = f2bf(v);
}

// ---------------- stage bodies (round-6 verified versions) ----------------

static __device__ __forceinline__ void enc1pool_body(const Params& p, int* nsh,
                                                     float* ws, float* bs) {
    int t = threadIdx.x;
    {
        int g = blockIdx.x * 256 + t;
        if (g < 5120) prep_swz<16, 32>(p.w_enc2, p.wb_enc2, g);          // NT=2 KT=5
        else {
            g -= 5120;
            if (g < 18432) prep_swz<32, 64>(p.w_enc3, p.wb_enc3, g);     // NT=4 KT=9
            else {
                g -= 18432;
                if (g < 18432) prep_swz<64, 32>(p.w_dec1, p.wb_dec1, g); // NT=2 KT=18
                else { g -= 18432; if (g < 4608) prep_swz<32, 16>(p.w_dec2, p.wb_dec2, g); }
            }
        }
    }
    if (t < 144) ws[t] = p.w_enc1[t];
    if (t < 16)  bs[t] = p.b_enc1[t];
    int base = blockIdx.x * 256;
    for (int e = t; e < 2304; e += 256)
        nsh[e] = __builtin_nontemporal_load(&p.neighs3[(size_t)base * 9 + e]);
    __syncthreads();
    float f[9];
#pragma unroll
    for (int k = 0; k < 9; ++k) { int j = nsh[t * 9 + k]; f[k] = (j < 0) ? 0.0f : p.features[j]; }
    float v[16];
#pragma unroll
    for (int co = 0; co < 16; ++co) {
        float a = bs[co];
#pragma unroll
        for (int k = 0; k < 9; ++k) a += f[k] * ws[co * 9 + k];
        v[co] = fmaxf(a, 0.0f);
    }
#pragma unroll
    for (int co = 0; co < 16; ++co) {
        v[co] = fmaxf(v[co], __shfl_xor(v[co], 1));
        v[co] = fmaxf(v[co], __shfl_xor(v[co], 2));
    }
    if ((t & 3) == 0) {
        unsigned int ov[8];
#pragma unroll
        for (int h = 0; h < 8; ++h)
            ov[h] = (unsigned int)f2bf(v[2 * h]) | (((unsigned int)f2bf(v[2 * h + 1])) << 16);
        uintx4* dst = (uintx4*)(p.x7p + (size_t)((base + t) >> 2) * 16);
        uintx4 o0 = {ov[0], ov[1], ov[2], ov[3]};
        uintx4 o1 = {ov[4], ov[5], ov[6], ov[7]};
        dst[0] = o0;
        dst[1] = o1;
    }
}

// generic MFMA conv with 4-deep gather ring; every stage = exactly 1024 blocks.
template <int CIN, int COUT, bool SHIFT, bool POOL, int TILES, int WN>
static __device__ __forceinline__ void conv_body(
    const unsigned short* __restrict__ src, const int* __restrict__ neigh,
    const unsigned short* __restrict__ wb, const float* __restrict__ bias,
    unsigned short* __restrict__ dst, int* nsh)
{
    constexpr int K   = 9 * CIN;
    constexpr int KT  = (K + 31) / 32;
    constexpr int NT  = COUT / 16;
    constexpr int WM  = 4 / WN;
    constexpr int NTW = NT / WN;
    constexpr int ROWS = WM * TILES * 16;
    constexpr int PF  = 4;
    static_assert(KT >= PF, "ring deeper than K-loop");
    int t = threadIdx.x;
    int rowbase = blockIdx.x * ROWS;
    for (int e = t; e < ROWS * 9; e += 256) {
        int j = __builtin_nontemporal_load(&neigh[(size_t)rowbase * 9 + e]);
        if (SHIFT) j = (j < 0) ? -1 : (j >> 2);
        nsh[e] = j;
    }
    __syncthreads();
    int lane = t & 63;
    int wave = t >> 6;
    int wm   = wave / WN;
    int wn   = wave - wm * WN;
    int m    = lane & 15;
    int quad = lane >> 4;
    int rbase9[TILES];
#pragma unroll
    for (int tl = 0; tl < TILES; ++tl)
        rbase9[tl] = ((wm * TILES + tl) * 16 + m) * 9;

    floatx4 acc[TILES][NTW];
#pragma unroll
    for (int tl = 0; tl < TILES; ++tl)
#pragma unroll
        for (int n = 0; n < NTW; ++n) acc[tl][n] = (floatx4){0.f, 0.f, 0.f, 0.f};

    auto gatherA = [&](int kt, bf16x8 (&dstA)[TILES]) {
        int k0 = kt * 32 + quad * 8;
#pragma unroll
        for (int tl = 0; tl < TILES; ++tl) {
            dstA[tl] = zero_bf16x8();
            if (k0 < K) {
                int j = nsh[rbase9[tl] + k0 / CIN];
                if (j >= 0) dstA[tl] = *(const bf16x8*)(src + (size_t)j * CIN + (k0 % CIN));
            }
        }
    };

    bf16x8 aB[PF][TILES];
#pragma unroll
    for (int p = 0; p < PF; ++p) gatherA(p, aB[p]);   // PF*TILES loads in flight

#pragma unroll
    for (int kt = 0; kt < KT; ++kt) {
#pragma unroll
        for (int n = 0; n < NTW; ++n) {
            int ng = wn * NTW + n;
            bf16x8 bfrag = *(const bf16x8*)(wb + ((size_t)(ng * KT + kt) * 64 + lane) * 8);
#pragma unroll
            for (int tl = 0; tl < TILES; ++tl)
                acc[tl][n] = __builtin_amdgcn_mfma_f32_16x16x32_bf16(aB[kt % PF][tl], bfrag, acc[tl][n], 0, 0, 0);
        }
        if (kt + PF < KT) gatherA(kt + PF, aB[kt % PF]);
    }

#pragma unroll
    for (int tl = 0; tl < TILES; ++tl) {
        int rg = wm * TILES + tl;
        if (POOL) {
            int pp = (rowbase >> 2) + rg * 4 + quad;
#pragma unroll
            for (int n = 0; n < NTW; ++n) {
                int cout = (wn * NTW + n) * 16 + m;
                float vm = fmaxf(fmaxf(acc[tl][n][0], acc[tl][n][1]), fmaxf(acc[tl][n][2], acc[tl][n][3]));
                float v  = fmaxf(vm + bias[cout], 0.0f);
                dst[(size_t)pp * COUT + cout] = f2bf(v);
            }
        } else {
            int grow = rowbase + rg * 16 + quad * 4;
#pragma unroll
            for (int n = 0; n < NTW; ++n) {
                int cout = (wn * NTW + n) * 16 + m;
                float bv = bias[cout];
#pragma unroll
                for (int r = 0; r < 4; ++r) {
                    float v = fmaxf(acc[tl][n][r] + bv, 0.0f);
                    dst[(size_t)(grow + r) * COUT + cout] = f2bf(v);
                }
            }
        }
    }
}

// head: Cin=16 bf16 -> 1 fp32; 1 row/thread, ring-4 (8 outstanding 16B loads).
static __device__ __forceinline__ float dot2(unsigned int u, const float* w) {
    return bf2f((unsigned short)(u & 0xffffu)) * w[0] + bf2f((unsigned short)(u >> 16)) * w[1];
}
static __device__ __forceinline__ void head_body(const Params& p, int* nsh, float* ws) {
    int t = threadIdx.x;
    if (t < 144) ws[t] = p.w_head[t];
    int base = blockIdx.x * 256;
    for (int e = t; e < 2304; e += 256)
        nsh[e] = __builtin_nontemporal_load(&p.neighs3[(size_t)base * 9 + e]);
    __syncthreads();
    int idx[9];
#pragma unroll
    for (int k = 0; k < 9; ++k) idx[k] = nsh[t * 9 + k];

    uint4 ra[4], rb[4];
    const uint4 z4 = make_uint4(0u, 0u, 0u, 0u);
#pragma unroll
    for (int pp = 0; pp < 4; ++pp) {
        ra[pp] = z4; rb[pp] = z4;
        int j = idx[pp];
        if (j >= 0) {
            const uint4* r = (const uint4*)(p.x8dec + (size_t)j * 16);
            ra[pp] = r[0]; rb[pp] = r[1];
        }
    }
    float acc = p.b_head[0];
#pragma unroll
    for (int k = 0; k < 9; ++k) {
        const float* wp = &ws[k * 16];
        uint4 r0 = ra[k & 3], r1 = rb[k & 3];
        acc += dot2(r0.x, wp)     + dot2(r0.y, wp + 2)  + dot2(r0.z, wp + 4)  + dot2(r0.w, wp + 6);
        acc += dot2(r1.x, wp + 8) + dot2(r1.y, wp + 10) + dot2(r1.z, wp + 12) + dot2(r1.w, wp + 14);
        if (k + 4 < 9) {
            int j = idx[k + 4];
            ra[k & 3] = z4; rb[k & 3] = z4;
            if (j >= 0) {
                const uint4* r = (const uint4*)(p.x8dec + (size_t)j * 16);
                ra[k & 3] = r[0]; rb[k & 3] = r[1];
            }
        }
    }
    p.out[base + t] = acc;
}

// ---------------- persistent fused kernel: 6 stages, 5 cheap grid barriers ----------------
__global__ __launch_bounds__(256, 4) void fused_kernel(Params p) {
    __shared__ __align__(16) int nsh[2304];
    __shared__ float ws[144];
    __shared__ float bs[16];

    enc1pool_body(p, nsh, ws, bs);                                                 // -> x7p
    gridsync(p.bar + 0, 1024);
    conv_body<16, 32, false, true,  2, 2>(p.x7p,   p.neighs2, p.wb_enc2, p.b_enc2, p.x6p,   nsh);
    gridsync(p.bar + 1, 1024);
    conv_body<32, 64, false, false, 1, 4>(p.x6p,   p.neighs1, p.wb_enc3, p.b_enc3, p.x6,    nsh);
    gridsync(p.bar + 2, 1024);
    conv_body<64, 32, true,  false, 2, 2>(p.x6,    p.neighs2, p.wb_dec1, p.b_dec1, p.x7dec, nsh);
    gridsync(p.bar + 3, 1024);
    conv_body<32, 16, true,  false, 4, 1>(p.x7dec, p.neighs3, p.wb_dec2, p.b_dec2, p.x8dec, nsh);
    gridsync(p.bar + 4, 1024);
    head_body(p, nsh, ws);
}

extern "C" void kernel_launch(void* const* d_in, const int* in_sizes, int n_in,
                              void* d_out, int out_size, void* d_ws, size_t ws_size,
                              hipStream_t stream) {
    Params P;
    P.features = (const float*)d_in[0];
    P.neighs3  = (const int*)d_in[4];
    P.neighs2  = (const int*)d_in[5];
    P.neighs1  = (const int*)d_in[6];
    P.w_enc1 = (const float*)d_in[7];  P.b_enc1 = (const float*)d_in[8];
    P.w_enc2 = (const float*)d_in[9];  P.b_enc2 = (const float*)d_in[10];
    P.w_enc3 = (const float*)d_in[11]; P.b_enc3 = (const float*)d_in[12];
    P.w_dec1 = (const float*)d_in[13]; P.b_dec1 = (const float*)d_in[14];
    P.w_dec2 = (const float*)d_in[15]; P.b_dec2 = (const float*)d_in[16];
    P.w_head = (const float*)d_in[17]; P.b_head = (const float*)d_in[18];

    char* ws = (char*)d_ws;
    size_t off = 0;
    P.wb_enc2 = (unsigned short*)(ws + off); off += 5120 * 2;
    P.wb_enc3 = (unsigned short*)(ws + off); off += 18432 * 2;
    P.wb_dec1 = (unsigned short*)(ws + off); off += 18432 * 2;
    P.wb_dec2 = (unsigned short*)(ws + off); off += 4608 * 2;
    P.x7p   = (unsigned short*)(ws + off); off += (size_t)NN2 * 16 * 2;
    P.x6p   = (unsigned short*)(ws + off); off += (size_t)NN1 * 32 * 2;
    P.x6    = (unsigned short*)(ws + off); off += (size_t)NN1 * 64 * 2;
    P.x7dec = (unsigned short*)(ws + off); off += (size_t)NN2 * 32 * 2;
    P.x8dec = (unsigned short*)(ws + off); off += (size_t)NN3 * 16 * 2;
    off = (off + 255) & ~(size_t)255;
    P.bar   = (unsigned int*)(ws + off);  off += 8 * sizeof(unsigned int);
    P.out = (float*)d_out;

    init_bar<<<1, 64, 0, stream>>>(P.bar);
    fused_kernel<<<1024, 256, 0, stream>>>(P);
}

// Round 10
// 638.535 us; speedup vs baseline: 1.1616x; 1.1616x over previous
//
#include <hip/hip_runtime.h>
#include <stdint.h>

#define NN3 262144
#define NN2 65536
#define NN1 16384

typedef __attribute__((ext_vector_type(8))) __bf16 bf16x8;
typedef __attribute__((ext_vector_type(4))) float floatx4;
typedef __attribute__((ext_vector_type(4))) unsigned int uintx4;

static __device__ __forceinline__ float bf2f(unsigned short u) {
    union { unsigned int i; float f; } v; v.i = ((unsigned int)u) << 16; return v.f;
}
static __device__ __forceinline__ unsigned short f2bf(float f) {
    union { float f; unsigned int i; } v; v.f = f;
    unsigned int x = v.i;
    return (unsigned short)((x + 0x7fffu + ((x >> 16) & 1u)) >> 16);
}
static __device__ __forceinline__ bf16x8 zero_bf16x8() {
    bf16x8 z;
#pragma unroll
    for (int i = 0; i < 8; ++i) z[i] = (__bf16)0.0f;
    return z;
}

struct Params {
    const float* features;
    const int* neighs3; const int* neighs2; const int* neighs1;
    const float* w_enc1; const float* b_enc1;
    const float* w_enc2; const float* b_enc2;
    const float* w_enc3; const float* b_enc3;
    const float* w_dec1; const float* b_dec1;
    const float* w_dec2; const float* b_dec2;
    const float* w_head; const float* b_head;
    unsigned short* wb_enc2; unsigned short* wb_enc3;
    unsigned short* wb_dec1; unsigned short* wb_dec2;
    unsigned short* x7p; unsigned short* x6p; unsigned short* x6;
    unsigned short* x7dec; unsigned short* x8dec;
    unsigned int* bar;
    float* out;
};

// ---------------- grid barrier v3: per-XCD leader writeback, NO invalidate ----------------
// Round 9's 100us/barrier = 1024 blocks x (buffer_wbl2 + buffer_inv), each a full
// L2-walk, ~128 serialized per XCD-L2. Fix:
//  (a) writeback: ONE leader block per XCD (elected via HW_REG_XCC_ID + atomic
//      ticket) does the release-fence AFTER all 1024 blocks arrived -> 8 parallel
//      wbl2s (~1us) instead of 1024.
//  (b) invalidate: NOT NEEDED. Every inter-stage buffer is written exactly once
//      and read only in later stages; kernel launch invalidated all caches, so no
//      XCD holds a stale copy of a line it hasn't touched this epoch. Consumer
//      misses go to MALL which has the written-back data; same-XCD reads hit the
//      local (clean) L2.
// All polls RELAXED (no cache ops). Spin guards: proceed after ~14ms worst-case ->
// a broken assumption shows as a wrong answer, never a dead container. Post-spin
// "memory" clobber + __syncthreads() stop the compiler hoisting gathers above the
// spin; waves are in-order so HW can't start them early either.
static __device__ __forceinline__ unsigned int xcc_id() {
    unsigned int x;
    asm("s_getreg_b32 %0, hwreg(HW_REG_XCC_ID)" : "=s"(x));
    return x & 7u;
}

static __device__ __forceinline__ void gridsync(unsigned int* bar) {
    __syncthreads();   // compiler emits per-wave s_waitcnt vmcnt(0) before s_barrier: all stores in L2
    if (threadIdx.x == 0) {
        unsigned int* arrive = bar;
        unsigned int* wbdone = bar + 1;
        unsigned int* lead   = bar + 2 + xcc_id();
        asm volatile("s_waitcnt vmcnt(0) lgkmcnt(0)" ::: "memory");
        __hip_atomic_fetch_add(arrive, 1u, __ATOMIC_RELAXED, __HIP_MEMORY_SCOPE_AGENT);
        if (__hip_atomic_fetch_add(lead, 1u, __ATOMIC_RELAXED, __HIP_MEMORY_SCOPE_AGENT) == 0u) {
            // XCD leader: wait for global arrival, then write back THIS XCD's L2 once.
            unsigned int s1 = 0;
            while (__hip_atomic_load(arrive, __ATOMIC_RELAXED, __HIP_MEMORY_SCOPE_AGENT) < 1024u) {
                __builtin_amdgcn_s_sleep(8);
                if (++s1 > (1u << 16)) break;
            }
            __builtin_amdgcn_fence(__ATOMIC_RELEASE, "agent");   // buffer_wbl2 (+wait) for this XCD
            __hip_atomic_fetch_add(wbdone, 1u, __ATOMIC_RELAXED, __HIP_MEMORY_SCOPE_AGENT);
        }
        unsigned int s2 = 0;
        while (__hip_atomic_load(wbdone, __ATOMIC_RELAXED, __HIP_MEMORY_SCOPE_AGENT) < 8u) {
            __builtin_amdgcn_s_sleep(8);
            if (++s2 > (1u << 16)) break;    // proceed-guard (also correct if an XCD had 0 blocks)
        }
        asm volatile("" ::: "memory");
    }
    __syncthreads();
}

__global__ __launch_bounds__(64) void init_bar(unsigned int* bar) {
    for (int i = threadIdx.x; i < 80; i += 64) bar[i] = 0u;
}

// ---------------- swizzled weight prep ----------------
//   out[((n*KT + kt)*64 + lane)*8 + e] = w[(n*16 + m)*K + kt*32 + quad*8 + e], k>=K zero-pad.
template <int CIN, int COUT>
static __device__ __forceinline__ void prep_swz(const float* __restrict__ w,
                                                unsigned short* __restrict__ out, int g) {
    constexpr int K = 9 * CIN, KT = (K + 31) / 32;
    int n = g / (KT * 512);
    int r = g - n * (KT * 512);
    int kt = r >> 9;
    int q = r & 511;
    int lane = q >> 3, e = q & 7;
    int m = lane & 15, quad = lane >> 4;
    int k = kt * 32 + quad * 8 + e;
    float v = (k < K) ? w[(n * 16 + m) * K + k] : 0.0f;
    out[g] = f2bf(v);
}

// ---------------- stage bodies (round-6 verified) ----------------

static __device__ __forceinline__ void enc1pool_body(const Params& p, int* nsh,
                                                     float* ws, float* bs) {
    int t = threadIdx.x;
    {
        int g = blockIdx.x * 256 + t;
        if (g < 5120) prep_swz<16, 32>(p.w_enc2, p.wb_enc2, g);          // NT=2 KT=5
        else {
            g -= 5120;
            if (g < 18432) prep_swz<32, 64>(p.w_enc3, p.wb_enc3, g);     // NT=4 KT=9
            else {
                g -= 18432;
                if (g < 18432) prep_swz<64, 32>(p.w_dec1, p.wb_dec1, g); // NT=2 KT=18
                else { g -= 18432; if (g < 4608) prep_swz<32, 16>(p.w_dec2, p.wb_dec2, g); }
            }
        }
    }
    if (t < 144) ws[t] = p.w_enc1[t];
    if (t < 16)  bs[t] = p.b_enc1[t];
    int base = blockIdx.x * 256;
    for (int e = t; e < 2304; e += 256)
        nsh[e] = __builtin_nontemporal_load(&p.neighs3[(size_t)base * 9 + e]);
    __syncthreads();
    float f[9];
#pragma unroll
    for (int k = 0; k < 9; ++k) { int j = nsh[t * 9 + k]; f[k] = (j < 0) ? 0.0f : p.features[j]; }
    float v[16];
#pragma unroll
    for (int co = 0; co < 16; ++co) {
        float a = bs[co];
#pragma unroll
        for (int k = 0; k < 9; ++k) a += f[k] * ws[co * 9 + k];
        v[co] = fmaxf(a, 0.0f);
    }
#pragma unroll
    for (int co = 0; co < 16; ++co) {
        v[co] = fmaxf(v[co], __shfl_xor(v[co], 1));
        v[co] = fmaxf(v[co], __shfl_xor(v[co], 2));
    }
    if ((t & 3) == 0) {
        unsigned int ov[8];
#pragma unroll
        for (int h = 0; h < 8; ++h)
            ov[h] = (unsigned int)f2bf(v[2 * h]) | (((unsigned int)f2bf(v[2 * h + 1])) << 16);
        uintx4* dst = (uintx4*)(p.x7p + (size_t)((base + t) >> 2) * 16);
        uintx4 o0 = {ov[0], ov[1], ov[2], ov[3]};
        uintx4 o1 = {ov[4], ov[5], ov[6], ov[7]};
        dst[0] = o0;
        dst[1] = o1;
    }
}

template <int CIN, int COUT, bool SHIFT, bool POOL, int TILES, int WN>
static __device__ __forceinline__ void conv_body(
    const unsigned short* __restrict__ src, const int* __restrict__ neigh,
    const unsigned short* __restrict__ wb, const float* __restrict__ bias,
    unsigned short* __restrict__ dst, int* nsh)
{
    constexpr int K   = 9 * CIN;
    constexpr int KT  = (K + 31) / 32;
    constexpr int NT  = COUT / 16;
    constexpr int WM  = 4 / WN;
    constexpr int NTW = NT / WN;
    constexpr int ROWS = WM * TILES * 16;
    constexpr int PF  = 4;
    static_assert(KT >= PF, "ring deeper than K-loop");
    int t = threadIdx.x;
    int rowbase = blockIdx.x * ROWS;
    for (int e = t; e < ROWS * 9; e += 256) {
        int j = __builtin_nontemporal_load(&neigh[(size_t)rowbase * 9 + e]);
        if (SHIFT) j = (j < 0) ? -1 : (j >> 2);
        nsh[e] = j;
    }
    __syncthreads();
    int lane = t & 63;
    int wave = t >> 6;
    int wm   = wave / WN;
    int wn   = wave - wm * WN;
    int m    = lane & 15;
    int quad = lane >> 4;
    int rbase9[TILES];
#pragma unroll
    for (int tl = 0; tl < TILES; ++tl)
        rbase9[tl] = ((wm * TILES + tl) * 16 + m) * 9;

    floatx4 acc[TILES][NTW];
#pragma unroll
    for (int tl = 0; tl < TILES; ++tl)
#pragma unroll
        for (int n = 0; n < NTW; ++n) acc[tl][n] = (floatx4){0.f, 0.f, 0.f, 0.f};

    auto gatherA = [&](int kt, bf16x8 (&dstA)[TILES]) {
        int k0 = kt * 32 + quad * 8;
#pragma unroll
        for (int tl = 0; tl < TILES; ++tl) {
            dstA[tl] = zero_bf16x8();
            if (k0 < K) {
                int j = nsh[rbase9[tl] + k0 / CIN];
                if (j >= 0) dstA[tl] = *(const bf16x8*)(src + (size_t)j * CIN + (k0 % CIN));
            }
        }
    };

    bf16x8 aB[PF][TILES];
#pragma unroll
    for (int p = 0; p < PF; ++p) gatherA(p, aB[p]);   // PF*TILES loads in flight

#pragma unroll
    for (int kt = 0; kt < KT; ++kt) {
#pragma unroll
        for (int n = 0; n < NTW; ++n) {
            int ng = wn * NTW + n;
            bf16x8 bfrag = *(const bf16x8*)(wb + ((size_t)(ng * KT + kt) * 64 + lane) * 8);
#pragma unroll
            for (int tl = 0; tl < TILES; ++tl)
                acc[tl][n] = __builtin_amdgcn_mfma_f32_16x16x32_bf16(aB[kt % PF][tl], bfrag, acc[tl][n], 0, 0, 0);
        }
        if (kt + PF < KT) gatherA(kt + PF, aB[kt % PF]);
    }

#pragma unroll
    for (int tl = 0; tl < TILES; ++tl) {
        int rg = wm * TILES + tl;
        if (POOL) {
            int pp = (rowbase >> 2) + rg * 4 + quad;
#pragma unroll
            for (int n = 0; n < NTW; ++n) {
                int cout = (wn * NTW + n) * 16 + m;
                float vm = fmaxf(fmaxf(acc[tl][n][0], acc[tl][n][1]), fmaxf(acc[tl][n][2], acc[tl][n][3]));
                float v  = fmaxf(vm + bias[cout], 0.0f);
                dst[(size_t)pp * COUT + cout] = f2bf(v);
            }
        } else {
            int grow = rowbase + rg * 16 + quad * 4;
#pragma unroll
            for (int n = 0; n < NTW; ++n) {
                int cout = (wn * NTW + n) * 16 + m;
                float bv = bias[cout];
#pragma unroll
                for (int r = 0; r < 4; ++r) {
                    float v = fmaxf(acc[tl][n][r] + bv, 0.0f);
                    dst[(size_t)(grow + r) * COUT + cout] = f2bf(v);
                }
            }
        }
    }
}

static __device__ __forceinline__ float dot2(unsigned int u, const float* w) {
    return bf2f((unsigned short)(u & 0xffffu)) * w[0] + bf2f((unsigned short)(u >> 16)) * w[1];
}
static __device__ __forceinline__ void head_body(const Params& p, int* nsh, float* ws) {
    int t = threadIdx.x;
    if (t < 144) ws[t] = p.w_head[t];
    int base = blockIdx.x * 256;
    for (int e = t; e < 2304; e += 256)
        nsh[e] = __builtin_nontemporal_load(&p.neighs3[(size_t)base * 9 + e]);
    __syncthreads();
    int idx[9];
#pragma unroll
    for (int k = 0; k < 9; ++k) idx[k] = nsh[t * 9 + k];

    uint4 ra[4], rb[4];
    const uint4 z4 = make_uint4(0u, 0u, 0u, 0u);
#pragma unroll
    for (int pp = 0; pp < 4; ++pp) {
        ra[pp] = z4; rb[pp] = z4;
        int j = idx[pp];
        if (j >= 0) {
            const uint4* r = (const uint4*)(p.x8dec + (size_t)j * 16);
            ra[pp] = r[0]; rb[pp] = r[1];
        }
    }
    float acc = p.b_head[0];
#pragma unroll
    for (int k = 0; k < 9; ++k) {
        const float* wp = &ws[k * 16];
        uint4 r0 = ra[k & 3], r1 = rb[k & 3];
        acc += dot2(r0.x, wp)     + dot2(r0.y, wp + 2)  + dot2(r0.z, wp + 4)  + dot2(r0.w, wp + 6);
        acc += dot2(r1.x, wp + 8) + dot2(r1.y, wp + 10) + dot2(r1.z, wp + 12) + dot2(r1.w, wp + 14);
        if (k + 4 < 9) {
            int j = idx[k + 4];
            ra[k & 3] = z4; rb[k & 3] = z4;
            if (j >= 0) {
                const uint4* r = (const uint4*)(p.x8dec + (size_t)j * 16);
                ra[k & 3] = r[0]; rb[k & 3] = r[1];
            }
        }
    }
    p.out[base + t] = acc;
}

// ---------------- persistent fused kernel: 6 stages, 5 leader-writeback barriers ----------------
__global__ __launch_bounds__(256, 4) void fused_kernel(Params p) {
    __shared__ __align__(16) int nsh[2304];
    __shared__ float ws[144];
    __shared__ float bs[16];

    enc1pool_body(p, nsh, ws, bs);                                                 // -> x7p, wb_*
    gridsync(p.bar + 0);
    conv_body<16, 32, false, true,  2, 2>(p.x7p,   p.neighs2, p.wb_enc2, p.b_enc2, p.x6p,   nsh);
    gridsync(p.bar + 16);
    conv_body<32, 64, false, false, 1, 4>(p.x6p,   p.neighs1, p.wb_enc3, p.b_enc3, p.x6,    nsh);
    gridsync(p.bar + 32);
    conv_body<64, 32, true,  false, 2, 2>(p.x6,    p.neighs2, p.wb_dec1, p.b_dec1, p.x7dec, nsh);
    gridsync(p.bar + 48);
    conv_body<32, 16, true,  false, 4, 1>(p.x7dec, p.neighs3, p.wb_dec2, p.b_dec2, p.x8dec, nsh);
    gridsync(p.bar + 64);
    head_body(p, nsh, ws);
}

extern "C" void kernel_launch(void* const* d_in, const int* in_sizes, int n_in,
                              void* d_out, int out_size, void* d_ws, size_t ws_size,
                              hipStream_t stream) {
    Params P;
    P.features = (const float*)d_in[0];
    P.neighs3  = (const int*)d_in[4];
    P.neighs2  = (const int*)d_in[5];
    P.neighs1  = (const int*)d_in[6];
    P.w_enc1 = (const float*)d_in[7];  P.b_enc1 = (const float*)d_in[8];
    P.w_enc2 = (const float*)d_in[9];  P.b_enc2 = (const float*)d_in[10];
    P.w_enc3 = (const float*)d_in[11]; P.b_enc3 = (const float*)d_in[12];
    P.w_dec1 = (const float*)d_in[13]; P.b_dec1 = (const float*)d_in[14];
    P.w_dec2 = (const float*)d_in[15]; P.b_dec2 = (const float*)d_in[16];
    P.w_head = (const float*)d_in[17]; P.b_head = (const float*)d_in[18];

    char* ws = (char*)d_ws;
    size_t off = 0;
    P.wb_enc2 = (unsigned short*)(ws + off); off += 5120 * 2;
    P.wb_enc3 = (unsigned short*)(ws + off); off += 18432 * 2;
    P.wb_dec1 = (unsigned short*)(ws + off); off += 18432 * 2;
    P.wb_dec2 = (unsigned short*)(ws + off); off += 4608 * 2;
    P.x7p   = (unsigned short*)(ws + off); off += (size_t)NN2 * 16 * 2;
    P.x6p   = (unsigned short*)(ws + off); off += (size_t)NN1 * 32 * 2;
    P.x6    = (unsigned short*)(ws + off); off += (size_t)NN1 * 64 * 2;
    P.x7dec = (unsigned short*)(ws + off); off += (size_t)NN2 * 32 * 2;
    P.x8dec = (unsigned short*)(ws + off); off += (size_t)NN3 * 16 * 2;
    off = (off + 255) & ~(size_t)255;
    P.bar   = (unsigned int*)(ws + off);  off += 80 * sizeof(unsigned int);
    P.out = (float*)d_out;

    init_bar<<<1, 64, 0, stream>>>(P.bar);
    fused_kernel<<<1024, 256, 0, stream>>>(P);
}